// Round 3
// baseline (207.408 us; speedup 1.0000x reference)
//
#include <hip/hip_runtime.h>

#define NROWS 8192
#define KDIM  512

typedef __attribute__((ext_vector_type(8))) short bf16x8;   // 8 bf16 = 4 VGPRs
typedef __attribute__((ext_vector_type(4))) float f32x4;

typedef unsigned int u32;
typedef unsigned short u16;

// ---- round-to-nearest-even f32 -> bf16 (bits) ----
__device__ __forceinline__ u16 f2bf(float f) {
    u32 u = __float_as_uint(f);
    u32 rounding = 0x7FFFu + ((u >> 16) & 1u);
    return (u16)((u + rounding) >> 16);
}

// ---- async global->LDS, 16B per lane (wave-uniform base + lane*16) ----
__device__ __forceinline__ void gload_lds16(const void* g, void* l) {
    __builtin_amdgcn_global_load_lds(
        (const __attribute__((address_space(1))) u32*)g,
        (__attribute__((address_space(3))) u32*)l,
        16, 0, 0);
}

// =====================================================================
// Kernel 1: row-normalize (f32) -> bf16. One wave per row, 4 rows/block.
// =====================================================================
__global__ __launch_bounds__(256) void norm_cast_kernel(
        const float* __restrict__ x1, const float* __restrict__ x2,
        u16* __restrict__ o1, u16* __restrict__ o2) {
    const int wave = threadIdx.x >> 6;
    const int lane = threadIdx.x & 63;
    int row = blockIdx.x * 4 + wave;          // 0..16383

    const float* src;
    u16* dst;
    if (row < NROWS) { src = x1 + (size_t)row * KDIM;           dst = o1 + (size_t)row * KDIM; }
    else             { src = x2 + (size_t)(row - NROWS) * KDIM; dst = o2 + (size_t)(row - NROWS) * KDIM; }

    const float4* s4 = (const float4*)src + lane * 2;
    float4 a = s4[0];
    float4 b = s4[1];

    float ss = a.x*a.x + a.y*a.y + a.z*a.z + a.w*a.w
             + b.x*b.x + b.y*b.y + b.z*b.z + b.w*b.w;
    #pragma unroll
    for (int off = 32; off; off >>= 1) ss += __shfl_xor(ss, off);

    float inv = 1.0f / fmaxf(sqrtf(ss), 1e-8f);

    u16 h[8];
    h[0] = f2bf(a.x * inv); h[1] = f2bf(a.y * inv);
    h[2] = f2bf(a.z * inv); h[3] = f2bf(a.w * inv);
    h[4] = f2bf(b.x * inv); h[5] = f2bf(b.y * inv);
    h[6] = f2bf(b.z * inv); h[7] = f2bf(b.w * inv);

    uint4 o;
    o.x = (u32)h[0] | ((u32)h[1] << 16);
    o.y = (u32)h[2] | ((u32)h[3] << 16);
    o.z = (u32)h[4] | ((u32)h[5] << 16);
    o.w = (u32)h[6] | ((u32)h[7] << 16);
    *((uint4*)dst + lane) = o;
}

// =====================================================================
// Kernel 2: strip GEMM. Block = 256 rows x 1024-col strip, walked as 8
// sub-tiles of 256x128 (BK=64, 64 K-iterations). 8 waves (2M x 4N),
// wave-tile 128x32. Dbuf LDS 96 KiB, XOR-swizzle, 4-phase quads,
// counted vmcnt(3), setprio. Store pipelining: sub-tile s-1's stores
// issue 8/tile during sub-tile s (acc double-buffered accA/accB).
// LDS buf: A 256x128B @ +0, B 128x128B @ +32768; buf stride 49152.
// =====================================================================

__global__ __launch_bounds__(512, 2) void gemm_bt_kernel(
        const u16* __restrict__ A, const u16* __restrict__ B,
        float* __restrict__ C) {
    __shared__ __align__(1024) char lds[98304];

    // bijective XCD swizzle (nwg = 256, divisible by 8)
    const int nwg = gridDim.x;
    const int bid = blockIdx.x;
    const int wg  = (bid & 7) * (nwg >> 3) + (bid >> 3);
    const int tile_m = (wg >> 3) << 8;    // 32 m-tiles of 256
    const int strip  = (wg & 7) << 10;    // 8 strips of 1024

    const int tid  = threadIdx.x;
    const int wid  = tid >> 6;
    const int lane = tid & 63;
    const int wm   = wid >> 2;      // 0..1  (M)
    const int wn   = wid & 3;       // 0..3  (N)
    const int fr   = lane & 15;
    const int q    = lane >> 4;

    // ds-read constants
    const int xr     = (fr & 7) << 4;
    const int colsw0 = (q * 16) ^ xr;
    const int colsw1 = (64 + q * 16) ^ xr;
    const int aRowB  = (wm * 128 + fr) * 128;   // byte row base in A region

    // staging constants: src col = dest col XOR'd by row&7 (both sides rule)
    const int s_cl     = (lane & 7) << 4;
    const int csrc_off = ((lane & 7) ^ ((lane >> 3) & 7)) << 4;

    f32x4  accA[8][2], accB[8][2];
    bf16x8 af[4][2];     // current A MH-half: 4 m-frags x 2 kk
    bf16x8 bf2[2][2];    // B frags: 2 NH x 2 kk

#define ABUF(b) (lds + (b) * 49152)
#define BBUF(b) (lds + (b) * 49152 + 32768)
#define BAR()   __builtin_amdgcn_s_barrier()
#define LGKM0() asm volatile("s_waitcnt lgkmcnt(0)")
#define VM3     asm volatile("s_waitcnt vmcnt(3)" ::: "memory");
#define VM0     asm volatile("s_waitcnt vmcnt(0)" ::: "memory");
#define VMX

// stage A group g (128 rows, 2 instr/thread) of K-tile index T into buf b
#define STAGE_A(b, g, T) do {                                                  \
    if ((T) < 64) {                                                            \
        const int _kb = ((T) & 7) * 128;                                       \
        _Pragma("unroll")                                                      \
        for (int _it = 0; _it < 2; ++_it) {                                    \
            const int _row = _it * 128 + (g) * 64 + (tid >> 3);                \
            gload_lds16((const char*)A + (size_t)(tile_m + _row) * (KDIM * 2)  \
                            + _kb + csrc_off,                                  \
                        ABUF(b) + _row * 128 + s_cl);                          \
        }                                                                      \
    }                                                                          \
} while (0)

// stage B group g (64 rows, 1 instr/thread) of K-tile index T into buf b
#define STAGE_B(b, g, T) do {                                                  \
    if ((T) < 64) {                                                            \
        const int _kb = ((T) & 7) * 128;                                       \
        const int _tn = strip + (((T) >> 3) << 7);                             \
        const int _row = (wid >> 1) * 32 + (g) * 16 + (wid & 1) * 8 + (lane >> 3); \
        gload_lds16((const char*)B + (size_t)(_tn + _row) * (KDIM * 2)         \
                        + _kb + csrc_off,                                      \
                    BBUF(b) + _row * 128 + s_cl);                              \
    }                                                                          \
} while (0)

#define LOAD_A(b, MH) do {                                                     \
    _Pragma("unroll")                                                          \
    for (int _m = 0; _m < 4; ++_m) {                                           \
        char* _p = ABUF(b) + aRowB + ((MH) * 64 + _m * 16) * 128;              \
        af[_m][0] = *(const bf16x8*)(_p + colsw0);                             \
        af[_m][1] = *(const bf16x8*)(_p + colsw1);                             \
    }                                                                          \
} while (0)

#define LOAD_BX(b, NH) do {                                                    \
    char* _p = BBUF(b) + (wn * 32 + (NH) * 16 + fr) * 128;                     \
    bf2[NH][0] = *(const bf16x8*)(_p + colsw0);                                \
    bf2[NH][1] = *(const bf16x8*)(_p + colsw1);                                \
} while (0)

#define MFMA_Q(MH, NH, ACCN) do {                                              \
    __builtin_amdgcn_s_setprio(1);                                             \
    _Pragma("unroll")                                                          \
    for (int _m = 0; _m < 4; ++_m)                                             \
    _Pragma("unroll")                                                          \
    for (int _kk = 0; _kk < 2; ++_kk)                                          \
        ACCN[(MH) * 4 + _m][NH] = __builtin_amdgcn_mfma_f32_16x16x32_bf16(     \
            af[_m][_kk], bf2[NH][_kk], ACCN[(MH) * 4 + _m][NH], 0, 0, 0);      \
    __builtin_amdgcn_s_setprio(0);                                             \
} while (0)

// 8 stores: drain chunk p (m-frag p) of the OLD accumulator
#define CHUNK(p, ACCO, OTN) do {                                               \
    _Pragma("unroll")                                                          \
    for (int _ni = 0; _ni < 2; ++_ni)                                          \
    _Pragma("unroll")                                                          \
    for (int _r = 0; _r < 4; ++_r)                                             \
        C[(size_t)(tile_m + wm * 128 + (p) * 16 + q * 4 + _r) * NROWS          \
          + (OTN) + wn * 32 + _ni * 16 + fr] = 16.0f * ACCO[p][_ni][_r];       \
} while (0)

// one K-tile: 4 phases; buf = p&1; stage t+1 into other buf, t+2 into own
#define TILE(p, BT, OTN, ACCN, ACCO, DOST, VMLINE) do {                        \
    if (DOST) CHUNK(p, ACCO, OTN);                                             \
    LOAD_A((p) & 1, 0); LOAD_BX((p) & 1, 0);                                   \
    STAGE_A(((p) & 1) ^ 1, 1, (BT) + (p) + 1);                                 \
    BAR(); LGKM0(); MFMA_Q(0, 0, ACCN); BAR();                                 \
    LOAD_BX((p) & 1, 1); STAGE_B(((p) & 1) ^ 1, 0, (BT) + (p) + 1);            \
    BAR(); LGKM0(); MFMA_Q(0, 1, ACCN); BAR();                                 \
    LOAD_A((p) & 1, 1); STAGE_A((p) & 1, 0, (BT) + (p) + 2);                   \
    BAR(); LGKM0(); MFMA_Q(1, 1, ACCN); BAR();                                 \
    STAGE_B((p) & 1, 1, (BT) + (p) + 2);                                       \
    VMLINE BAR(); MFMA_Q(1, 0, ACCN); BAR();                                   \
} while (0)

#define ZERO_ACC(ACCN) do {                                                    \
    _Pragma("unroll")                                                          \
    for (int _i = 0; _i < 8; ++_i) {                                           \
        ACCN[_i][0] = (f32x4){0.f, 0.f, 0.f, 0.f};                             \
        ACCN[_i][1] = (f32x4){0.f, 0.f, 0.f, 0.f};                             \
    }                                                                          \
} while (0)

#define SUBTILE(BT, OTN, ACCN, ACCO, DOST, V6, V7) do {                        \
    ZERO_ACC(ACCN);                                                            \
    TILE(0, BT, OTN, ACCN, ACCO, DOST, VM3);                                   \
    TILE(1, BT, OTN, ACCN, ACCO, DOST, VM3);                                   \
    TILE(2, BT, OTN, ACCN, ACCO, DOST, VM3);                                   \
    TILE(3, BT, OTN, ACCN, ACCO, DOST, VM3);                                   \
    TILE(4, BT, OTN, ACCN, ACCO, DOST, VM3);                                   \
    TILE(5, BT, OTN, ACCN, ACCO, DOST, VM3);                                   \
    TILE(6, BT, OTN, ACCN, ACCO, DOST, V6);                                    \
    TILE(7, BT, OTN, ACCN, ACCO, DOST, V7);                                    \
} while (0)

    // ---- prologue: stage tile0 fully + tile1's {Ag0, Bg1} ----
    STAGE_A(0, 0, 0); STAGE_A(0, 1, 0); STAGE_B(0, 0, 0); STAGE_B(0, 1, 0);
    STAGE_A(1, 0, 1); STAGE_B(1, 1, 1);
    VM3 BAR();

    // ---- subtile pair 0: s=0 (no stores), s=1 (drain accA/subtile0) ----
    SUBTILE(0, 0, accA, accB, 0, VM3, VM3);
    SUBTILE(8, strip, accB, accA, 1, VM3, VM3);

    // ---- middle pairs: si = 1..2  (s = 2si, 2si+1) ----
    for (int si = 1; si < 3; ++si) {
        const int btE = si * 16;
        SUBTILE(btE,     strip + (2 * si - 1) * 128, accA, accB, 1, VM3, VM3);
        SUBTILE(btE + 8, strip + (2 * si) * 128,     accB, accA, 1, VM3, VM3);
    }

    // ---- last pair: s=6, s=7 (tail: t=62 -> vmcnt(0), t=63 -> none) ----
    SUBTILE(48, strip + 5 * 128, accA, accB, 1, VM3, VM3);
    SUBTILE(56, strip + 6 * 128, accB, accA, 1, VM0, VMX);

    // ---- final: drain subtile 7 (accB) ----
    CHUNK(0, accB, strip + 7 * 128); CHUNK(1, accB, strip + 7 * 128);
    CHUNK(2, accB, strip + 7 * 128); CHUNK(3, accB, strip + 7 * 128);
    CHUNK(4, accB, strip + 7 * 128); CHUNK(5, accB, strip + 7 * 128);
    CHUNK(6, accB, strip + 7 * 128); CHUNK(7, accB, strip + 7 * 128);

#undef ABUF
#undef BBUF
#undef BAR
#undef LGKM0
#undef VM3
#undef VM0
#undef VMX
#undef STAGE_A
#undef STAGE_B
#undef LOAD_A
#undef LOAD_BX
#undef MFMA_Q
#undef CHUNK
#undef TILE
#undef ZERO_ACC
#undef SUBTILE
}

extern "C" void kernel_launch(void* const* d_in, const int* in_sizes, int n_in,
                              void* d_out, int out_size, void* d_ws, size_t ws_size,
                              hipStream_t stream) {
    const float* x1 = (const float*)d_in[0];
    const float* x2 = (const float*)d_in[1];
    float* out = (float*)d_out;

    u16* a_bf = (u16*)d_ws;                          // 8 MB
    u16* b_bf = a_bf + (size_t)NROWS * KDIM;         // 8 MB

    norm_cast_kernel<<<4096, 256, 0, stream>>>(x1, x2, a_bf, b_bf);

    gemm_bt_kernel<<<256, 512, 0, stream>>>(a_bf, b_bf, out);
}

// Round 4
// 136.424 us; speedup vs baseline: 1.5203x; 1.5203x over previous
//
#include <hip/hip_runtime.h>

#define NROWS 8192
#define KDIM  512

typedef __attribute__((ext_vector_type(8))) short bf16x8;   // 8 bf16 = 4 VGPRs
typedef __attribute__((ext_vector_type(4))) float f32x4;

typedef unsigned int u32;
typedef unsigned short u16;

// ---- round-to-nearest-even f32 -> bf16 (bits) ----
__device__ __forceinline__ u16 f2bf(float f) {
    u32 u = __float_as_uint(f);
    u32 rounding = 0x7FFFu + ((u >> 16) & 1u);
    return (u16)((u + rounding) >> 16);
}

// ---- async global->LDS, 16B per lane (wave-uniform base + lane*16) ----
__device__ __forceinline__ void gload_lds16(const void* g, void* l) {
    __builtin_amdgcn_global_load_lds(
        (const __attribute__((address_space(1))) u32*)g,
        (__attribute__((address_space(3))) u32*)l,
        16, 0, 0);
}

// =====================================================================
// Kernel 1: row-normalize (f32) -> bf16. One wave per row, 4 rows/block.
// =====================================================================
__global__ __launch_bounds__(256) void norm_cast_kernel(
        const float* __restrict__ x1, const float* __restrict__ x2,
        u16* __restrict__ o1, u16* __restrict__ o2) {
    const int wave = threadIdx.x >> 6;
    const int lane = threadIdx.x & 63;
    int row = blockIdx.x * 4 + wave;          // 0..16383

    const float* src;
    u16* dst;
    if (row < NROWS) { src = x1 + (size_t)row * KDIM;           dst = o1 + (size_t)row * KDIM; }
    else             { src = x2 + (size_t)(row - NROWS) * KDIM; dst = o2 + (size_t)(row - NROWS) * KDIM; }

    const float4* s4 = (const float4*)src + lane * 2;
    float4 a = s4[0];
    float4 b = s4[1];

    float ss = a.x*a.x + a.y*a.y + a.z*a.z + a.w*a.w
             + b.x*b.x + b.y*b.y + b.z*b.z + b.w*b.w;
    #pragma unroll
    for (int off = 32; off; off >>= 1) ss += __shfl_xor(ss, off);

    float inv = 1.0f / fmaxf(sqrtf(ss), 1e-8f);

    u16 h[8];
    h[0] = f2bf(a.x * inv); h[1] = f2bf(a.y * inv);
    h[2] = f2bf(a.z * inv); h[3] = f2bf(a.w * inv);
    h[4] = f2bf(b.x * inv); h[5] = f2bf(b.y * inv);
    h[6] = f2bf(b.z * inv); h[7] = f2bf(b.w * inv);

    uint4 o;
    o.x = (u32)h[0] | ((u32)h[1] << 16);
    o.y = (u32)h[2] | ((u32)h[3] << 16);
    o.z = (u32)h[4] | ((u32)h[5] << 16);
    o.w = (u32)h[6] | ((u32)h[7] << 16);
    *((uint4*)dst + lane) = o;
}

// =====================================================================
// Kernel 2: R2-verified 256x256 8-phase schedule, extended to a block
// output of 256x512 = two 256^2 sub-tiles via ONE continuous 16-tile
// K-loop (tiles 0-7 -> sub-tile 0, tiles 8-15 -> sub-tile 1).
// Tile T: A K-byte-offset = (T&7)*128; B rows = tile_n + (T>>3)*256.
// Sub-tile 0's 64 stores burst at the tile-8 boundary (oldest vmem ops,
// so all counted vmcnt(6) stay exactly correct; the i=4 PH4 wait
// force-drains them = the write floor). Single accumulator, zeroed at
// the boundary. Grid 512 (2 rounds). LDS/VGPR identical to R2.
// =====================================================================

__global__ __launch_bounds__(512, 2) void gemm_bt_kernel(
        const u16* __restrict__ A, const u16* __restrict__ B,
        float* __restrict__ C) {
    __shared__ __align__(1024) char lds[131072];

    // bijective XCD swizzle (nwg = 512, divisible by 8)
    const int nwg = gridDim.x;
    const int bid = blockIdx.x;
    const int wg  = (bid & 7) * (nwg >> 3) + (bid >> 3);
    const int tile_m = (wg >> 4) << 8;    // 32 m-tiles of 256
    const int tile_n = (wg & 15) << 9;    // 16 n-strips of 512

    const int tid  = threadIdx.x;
    const int wid  = tid >> 6;
    const int lane = tid & 63;
    const int wm   = wid >> 2;      // 0..1  (M)
    const int wn   = wid & 3;       // 0..3  (N)
    const int fr   = lane & 15;
    const int q    = lane >> 4;

    // staging constants
    const int s_rl0 = tid >> 3;           // 0..63
    const int s_cl  = (tid & 7) << 4;     // 0..112

    // ds-read constants
    const int xr     = (fr & 7) << 4;
    const int colsw0 = (q * 16) ^ xr;          // kk=0 fragment col (swizzled)
    const int colsw1 = (64 + q * 16) ^ xr;     // kk=1
    const int aRow   = ((wm << 7) + fr) << 7;            // byte row base in A region
    const int bRow   = (((wn << 6) + fr) << 7) + 32768;  // byte row base in B region

    f32x4  acc[8][4] = {};
    bf16x8 af[4][2];   // current A half (4 mi x 2 kk)
    bf16x8 bf[4][2];   // full B tile   (4 ni x 2 kk)

// stage one half-group: ISB A/B, BUF buffer, G group bit, T K-tile 0..15
#define STAGE(ISB, BUF, G, T) do {                                             \
    const u16* _g   = (ISB) ? B : A;                                           \
    const int _base = (ISB) ? (tile_n + (((T) >> 3) << 8)) : tile_m;           \
    char* _l = lds + (BUF) * 65536 + ((ISB) ? 32768 : 0);                      \
    _Pragma("unroll")                                                          \
    for (int _it = 0; _it < 2; ++_it) {                                        \
        int _rl  = _it * 64 + s_rl0;                                           \
        int _row = (ISB) ? (((_rl >> 5) << 6) + ((G) << 5) + (_rl & 31))       \
                         : (((_rl >> 6) << 7) + ((G) << 6) + (_rl & 63));      \
        int _csrc = s_cl ^ ((_row & 7) << 4);                                  \
        gload_lds16((const char*)_g + (size_t)(_base + _row) * (KDIM * 2)      \
                        + (((T) & 7) * 128) + _csrc,                           \
                    _l + _row * 128 + s_cl);                                   \
    }                                                                          \
} while (0)

#define LOAD_A(BUF, MH) do {                                                   \
    char* _l = lds + (BUF) * 65536;                                            \
    _Pragma("unroll")                                                          \
    for (int _m = 0; _m < 4; ++_m) {                                           \
        af[_m][0] = *(const bf16x8*)(_l + aRow + ((MH) * 4 + _m) * 2048 + colsw0); \
        af[_m][1] = *(const bf16x8*)(_l + aRow + ((MH) * 4 + _m) * 2048 + colsw1); \
    }                                                                          \
} while (0)

#define LOAD_B(BUF, NH) do {                                                   \
    char* _l = lds + (BUF) * 65536;                                            \
    _Pragma("unroll")                                                          \
    for (int _n = 0; _n < 2; ++_n) {                                           \
        bf[(NH) * 2 + _n][0] = *(const bf16x8*)(_l + bRow + ((NH) * 2 + _n) * 2048 + colsw0); \
        bf[(NH) * 2 + _n][1] = *(const bf16x8*)(_l + bRow + ((NH) * 2 + _n) * 2048 + colsw1); \
    }                                                                          \
} while (0)

#define MFMA_Q(MH, NH) do {                                                    \
    __builtin_amdgcn_s_setprio(1);                                             \
    _Pragma("unroll")                                                          \
    for (int _m = 0; _m < 4; ++_m)                                             \
    _Pragma("unroll")                                                          \
    for (int _n = 0; _n < 2; ++_n)                                             \
    _Pragma("unroll")                                                          \
    for (int _kk = 0; _kk < 2; ++_kk)                                          \
        acc[(MH) * 4 + _m][(NH) * 2 + _n] = __builtin_amdgcn_mfma_f32_16x16x32_bf16( \
            af[_m][_kk], bf[(NH) * 2 + _n][_kk], acc[(MH) * 4 + _m][(NH) * 2 + _n], 0, 0, 0); \
    __builtin_amdgcn_s_setprio(0);                                             \
} while (0)

// store one m-frag row-block of acc to C at n-base OTN
#define CHUNK(P, OTN) do {                                                     \
    _Pragma("unroll")                                                          \
    for (int _ni = 0; _ni < 4; ++_ni)                                          \
    _Pragma("unroll")                                                          \
    for (int _r = 0; _r < 4; ++_r)                                             \
        C[(size_t)(tile_m + wm * 128 + (P) * 16 + q * 4 + _r) * NROWS          \
          + (OTN) + wn * 64 + _ni * 16 + fr] = 16.0f * acc[(P)][_ni][_r];      \
} while (0)

#define BAR()   __builtin_amdgcn_s_barrier()
#define LGKM0() asm volatile("s_waitcnt lgkmcnt(0)")

    // ---- prologue: tile0 (all 4 groups) + tile1 (Ag0,Bg0,Bg1) = 14 loads ----
    STAGE(0, 0, 0, 0); STAGE(1, 0, 0, 0); STAGE(1, 0, 1, 0); STAGE(0, 0, 1, 0);
    STAGE(0, 1, 0, 1); STAGE(1, 1, 0, 1); STAGE(1, 1, 1, 1);
    asm volatile("s_waitcnt vmcnt(6)" ::: "memory");   // tile0 complete
    BAR();

    // ---- main: 7 iterations x 2 tiles = tiles 0..13, prefetch thru 15 ----
    #pragma unroll
    for (int i = 0; i < 7; ++i) {
        const int t1 = 2 * i + 1;
        const int tp0 = 2 * i + 2, tp1 = 2 * i + 3;

        if (i == 4) {
            // sub-tile 0 complete (tiles 0..7 consumed). Burst its stores:
            // oldest vmem ops -> all later counted waits stay exact; the
            // PH4 vmcnt(6) below force-drains them (write floor).
            CHUNK(0, tile_n); CHUNK(1, tile_n); CHUNK(2, tile_n); CHUNK(3, tile_n);
            CHUNK(4, tile_n); CHUNK(5, tile_n); CHUNK(6, tile_n); CHUNK(7, tile_n);
            #pragma unroll
            for (int _i = 0; _i < 8; ++_i)
                #pragma unroll
                for (int _j = 0; _j < 4; ++_j)
                    acc[_i][_j] = (f32x4){0.f, 0.f, 0.f, 0.f};
        }

        // PH1: quad(0,0) of tile t0 (buf0)
        LOAD_A(0, 0); LOAD_B(0, 0);
        STAGE(0, 1, 1, t1);                    // buf1.Ag1 <- tile t1
        asm volatile("s_waitcnt lgkmcnt(8)");
        BAR(); LGKM0(); MFMA_Q(0, 0); BAR();
        // PH2: quad(0,1)
        LOAD_B(0, 1);
        STAGE(0, 0, 0, tp0);                   // buf0.Ag0 <- tile t0+2
        BAR(); LGKM0(); MFMA_Q(0, 1); BAR();
        // PH3: quad(1,1)
        LOAD_A(0, 1);
        STAGE(1, 0, 0, tp0);                   // buf0.Bg0
        BAR(); LGKM0(); MFMA_Q(1, 1); BAR();
        // PH4: quad(1,0) — vmcnt once per K-tile
        STAGE(1, 0, 1, tp0);                   // buf0.Bg1
        asm volatile("s_waitcnt vmcnt(6)" ::: "memory");   // tile t1 complete
        BAR(); MFMA_Q(1, 0); BAR();
        // PH5: quad(0,0) of tile t1 (buf1)
        LOAD_A(1, 0); LOAD_B(1, 0);
        STAGE(0, 0, 1, tp0);                   // buf0.Ag1
        asm volatile("s_waitcnt lgkmcnt(8)");
        BAR(); LGKM0(); MFMA_Q(0, 0); BAR();
        // PH6: quad(0,1)
        LOAD_B(1, 1);
        STAGE(0, 1, 0, tp1);                   // buf1.Ag0 <- tile t1+2
        BAR(); LGKM0(); MFMA_Q(0, 1); BAR();
        // PH7: quad(1,1)
        LOAD_A(1, 1);
        STAGE(1, 1, 0, tp1);                   // buf1.Bg0
        BAR(); LGKM0(); MFMA_Q(1, 1); BAR();
        // PH8: quad(1,0)
        STAGE(1, 1, 1, tp1);                   // buf1.Bg1
        asm volatile("s_waitcnt vmcnt(6)" ::: "memory");   // tile t0+2 complete
        BAR(); MFMA_Q(1, 0); BAR();
    }

    // ---- tail: tiles 14 (buf0) and 15 (buf1), no further prefetch ----
    LOAD_A(0, 0); LOAD_B(0, 0);
    STAGE(0, 1, 1, 15);                        // buf1.Ag1 <- tile 15 (last load)
    BAR(); LGKM0(); MFMA_Q(0, 0); BAR();
    LOAD_B(0, 1);
    BAR(); LGKM0(); MFMA_Q(0, 1); BAR();
    LOAD_A(0, 1);
    BAR(); LGKM0(); MFMA_Q(1, 1); BAR();
    asm volatile("s_waitcnt vmcnt(0)" ::: "memory");       // tile 15 complete
    BAR(); MFMA_Q(1, 0); BAR();
    LOAD_A(1, 0); LOAD_B(1, 0);
    BAR(); LGKM0(); MFMA_Q(0, 0); BAR();
    LOAD_B(1, 1);
    BAR(); LGKM0(); MFMA_Q(0, 1); BAR();
    LOAD_A(1, 1);
    BAR(); LGKM0(); MFMA_Q(1, 1); BAR();
    MFMA_Q(1, 0);

    // ---- final epilogue: sub-tile 1 (n-base tile_n + 256) ----
    CHUNK(0, tile_n + 256); CHUNK(1, tile_n + 256);
    CHUNK(2, tile_n + 256); CHUNK(3, tile_n + 256);
    CHUNK(4, tile_n + 256); CHUNK(5, tile_n + 256);
    CHUNK(6, tile_n + 256); CHUNK(7, tile_n + 256);

#undef STAGE
#undef LOAD_A
#undef LOAD_B
#undef MFMA_Q
#undef CHUNK
#undef BAR
#undef LGKM0
}

extern "C" void kernel_launch(void* const* d_in, const int* in_sizes, int n_in,
                              void* d_out, int out_size, void* d_ws, size_t ws_size,
                              hipStream_t stream) {
    const float* x1 = (const float*)d_in[0];
    const float* x2 = (const float*)d_in[1];
    float* out = (float*)d_out;

    u16* a_bf = (u16*)d_ws;                          // 8 MB
    u16* b_bf = a_bf + (size_t)NROWS * KDIM;         // 8 MB

    norm_cast_kernel<<<4096, 256, 0, stream>>>(x1, x2, a_bf, b_bf);

    const int grid = (NROWS / 256) * (NROWS / 512);  // 512
    gemm_bt_kernel<<<grid, 512, 0, stream>>>(a_bf, b_bf, out);
}